// Round 8
// baseline (664.327 us; speedup 1.0000x reference)
//
#include <hip/hip_runtime.h>
#include <math.h>

// Problem constants
#define B_    64
#define S_    2048
#define E_    300
#define H_    150
#define C_    34
#define NROWS 50000
#define PBLK  512                 // stream blocks: 2/CU despite 77KB LDS
#define RPB   98                  // rows per block (512*98 = 50176 >= 50000)
#define PJ    (B_ * E_ + B_)      // 19264: h-sums [b*300+e] ++ l-sums [b]
#define SCALE 0.057735026918962584f   // 1/sqrt(300)

// ---- cnt matrix: byte counts, layout [r][b] (64B per row line) ----
__global__ __launch_bounds__(256) void zero_cnt(unsigned int* __restrict__ c) {
    c[blockIdx.x * 256 + threadIdx.x] = 0u;   // grid 3125*256 = 800000 words = 3.2MB
}

__global__ __launch_bounds__(256) void scatter_cnt(
    const int* __restrict__ x, unsigned int* __restrict__ cnt32)
{
    const int i = blockIdx.x * 256 + threadIdx.x;   // token id, grid 512*256
    const int r = x[i];
    const int b = i >> 11;                          // i / 2048
    const int idx = r * 64 + b;
    atomicAdd(&cnt32[idx >> 2], 1u << ((idx & 3) * 8));   // byte counter
}

// ---- stage 1: stream all rows; w1=exp(scale*q.row); scatter to <=64 b's ----
// Row slicing: lane holds e = lane + 64k, k=0..4 (k=4 only lanes<44).
// LDS accumulator hp[64][300] fp32; lane-stride-1 ds_add => conflict-free.
__global__ __launch_bounds__(256) void stage1_pass(
    const float* __restrict__ emb, const float* __restrict__ query,
    const unsigned char* __restrict__ cntb, float* __restrict__ p_h)
{
    __shared__ float hp[B_ * E_];   // 76.8 KB (r4 proved >64KB static LDS works)
    __shared__ float lp[B_];
    const int tid = threadIdx.x, wv = tid >> 6, lane = tid & 63;
    for (int j = tid; j < B_ * E_; j += 256) hp[j] = 0.f;
    if (tid < B_) lp[tid] = 0.f;

    float qf[5];
    #pragma unroll
    for (int k = 0; k < 5; ++k) {
        const int e = lane + 64 * k;
        qf[k] = (e < E_) ? query[e] * SCALE : 0.f;
    }
    __syncthreads();

    const int r0    = blockIdx.x * RPB;
    const int r_end = min(r0 + RPB, NROWS);
    const int rw0   = r0 + wv;

    if (rw0 < r_end) {
        float f[5], cf;
        {   // preload first row
            const float* rp = emb + (size_t)rw0 * E_;
            f[0] = rp[lane];       f[1] = rp[lane + 64];
            f[2] = rp[lane + 128]; f[3] = rp[lane + 192];
            f[4] = (lane < 44) ? rp[lane + 256] : 0.f;
            cf = (float)cntb[(size_t)rw0 * 64 + lane];
        }
        for (int r = rw0; r < r_end; r += 4) {
            const int rn = (r + 4 < r_end) ? r + 4 : r;   // clamped prefetch
            float fn[5], cfn;
            {
                const float* rp = emb + (size_t)rn * E_;
                fn[0] = rp[lane];       fn[1] = rp[lane + 64];
                fn[2] = rp[lane + 128]; fn[3] = rp[lane + 192];
                fn[4] = (lane < 44) ? rp[lane + 256] : 0.f;
                cfn = (float)cntb[(size_t)rn * 64 + lane];
            }
            // score + weight for current row
            float d = f[0]*qf[0] + f[1]*qf[1] + f[2]*qf[2] + f[3]*qf[3] + f[4]*qf[4];
            #pragma unroll
            for (int off = 32; off > 0; off >>= 1) d += __shfl_xor(d, off);
            const float w1 = __expf(d);
            // scatter to batches with nonzero count (~2.6 per row)
            unsigned long long mk = __ballot(cf > 0.f);
            while (mk) {
                const int j = __ffsll((unsigned long long)mk) - 1;
                mk &= mk - 1;
                const float wt = __shfl(cf, j) * w1;
                float* dst = hp + j * E_;
                atomicAdd(&dst[lane],       wt * f[0]);
                atomicAdd(&dst[lane + 64],  wt * f[1]);
                atomicAdd(&dst[lane + 128], wt * f[2]);
                atomicAdd(&dst[lane + 192], wt * f[3]);
                if (lane < 44) atomicAdd(&dst[lane + 256], wt * f[4]);
                if (lane == 0) atomicAdd(&lp[j], wt);
            }
            #pragma unroll
            for (int k = 0; k < 5; ++k) f[k] = fn[k];
            cf = cfn;
        }
    }
    __syncthreads();
    float* o = p_h + (size_t)blockIdx.x * PJ;
    for (int j = tid; j < B_ * E_; j += 256) o[j] = hp[j];
    if (tid < B_) o[B_ * E_ + tid] = lp[tid];
}

// ---- stage 2: per hit, score = v2[b].row (v2 is 77KB, L2-hot) ----
__global__ __launch_bounds__(256) void stage2_pass(
    const float* __restrict__ emb, const float* __restrict__ v2g,
    const unsigned char* __restrict__ cntb, float* __restrict__ p_h)
{
    __shared__ float hp[B_ * E_];
    __shared__ float lp[B_];
    const int tid = threadIdx.x, wv = tid >> 6, lane = tid & 63;
    for (int j = tid; j < B_ * E_; j += 256) hp[j] = 0.f;
    if (tid < B_) lp[tid] = 0.f;
    __syncthreads();

    const int r0    = blockIdx.x * RPB;
    const int r_end = min(r0 + RPB, NROWS);
    const int rw0   = r0 + wv;

    if (rw0 < r_end) {
        float f[5], cf;
        {
            const float* rp = emb + (size_t)rw0 * E_;
            f[0] = rp[lane];       f[1] = rp[lane + 64];
            f[2] = rp[lane + 128]; f[3] = rp[lane + 192];
            f[4] = (lane < 44) ? rp[lane + 256] : 0.f;
            cf = (float)cntb[(size_t)rw0 * 64 + lane];
        }
        for (int r = rw0; r < r_end; r += 4) {
            const int rn = (r + 4 < r_end) ? r + 4 : r;
            float fn[5], cfn;
            {
                const float* rp = emb + (size_t)rn * E_;
                fn[0] = rp[lane];       fn[1] = rp[lane + 64];
                fn[2] = rp[lane + 128]; fn[3] = rp[lane + 192];
                fn[4] = (lane < 44) ? rp[lane + 256] : 0.f;
                cfn = (float)cntb[(size_t)rn * 64 + lane];
            }
            unsigned long long mk = __ballot(cf > 0.f);
            while (mk) {
                const int j = __ffsll((unsigned long long)mk) - 1;
                mk &= mk - 1;
                const float cb = __shfl(cf, j);
                const float* vb = v2g + j * E_;
                float d = f[0]*vb[lane] + f[1]*vb[lane + 64]
                        + f[2]*vb[lane + 128] + f[3]*vb[lane + 192];
                if (lane < 44) d += f[4]*vb[lane + 256];
                #pragma unroll
                for (int off = 32; off > 0; off >>= 1) d += __shfl_xor(d, off);
                const float wt = cb * __expf(d);
                float* dst = hp + j * E_;
                atomicAdd(&dst[lane],       wt * f[0]);
                atomicAdd(&dst[lane + 64],  wt * f[1]);
                atomicAdd(&dst[lane + 128], wt * f[2]);
                atomicAdd(&dst[lane + 192], wt * f[3]);
                if (lane < 44) atomicAdd(&dst[lane + 256], wt * f[4]);
                if (lane == 0) atomicAdd(&lp[j], wt);
            }
            #pragma unroll
            for (int k = 0; k < 5; ++k) f[k] = fn[k];
            cf = cfn;
        }
    }
    __syncthreads();
    float* o = p_h + (size_t)blockIdx.x * PJ;
    for (int j = tid; j < B_ * E_; j += 256) o[j] = hp[j];
    if (tid < B_) o[B_ * E_ + tid] = lp[tid];
}

// ---- reduce 512 partial slices -> raw sums (19264 j's, 301*64) ----
__global__ __launch_bounds__(256) void reduce_parts(
    const float* __restrict__ p_h, float* __restrict__ acc_out)
{
    const int j  = blockIdx.x * 64 + (threadIdx.x & 63);
    const int pc = threadIdx.x >> 6;
    float a = 0.f;
    for (int p = pc; p < PBLK; p += 4)
        a += p_h[(size_t)p * PJ + j];
    __shared__ float s[4][64];
    s[pc][threadIdx.x & 63] = a;
    __syncthreads();
    if (pc == 0)
        acc_out[j] = (s[0][threadIdx.x] + s[1][threadIdx.x])
                   + (s[2][threadIdx.x] + s[3][threadIdx.x]);
}

// ---- h1 = acc/l ; v2 = (h1 @ W) @ W^T (k2-elimination) ----
__global__ __launch_bounds__(320) void qv_kernel(
    const float* __restrict__ acc, const float* __restrict__ W,
    float* __restrict__ h1out, float* __restrict__ v2out)
{
    const int b = blockIdx.x, tid = threadIdx.x;
    __shared__ float sh[E_], sq[H_];
    const float linv = 1.f / acc[B_ * E_ + b];
    if (tid < E_) {
        const float h = acc[b * E_ + tid] * linv;
        sh[tid] = h;
        h1out[b * E_ + tid] = h;
    }
    __syncthreads();
    if (tid < H_) {
        float a = 0.f;
        for (int e = 0; e < E_; ++e) a += sh[e] * W[e * H_ + tid];
        sq[tid] = a;
    }
    __syncthreads();
    if (tid < E_) {
        float a = 0.f;
        const float* wr = W + (size_t)tid * H_;
        for (int h = 0; h < H_; ++h) a += sq[h] * wr[h];
        v2out[b * E_ + tid] = a;
    }
}

// ---- h2 = acc2/l2 ; out = [h1;h2] @ Wout + bias ----
__global__ __launch_bounds__(320) void scores_kernel(
    const float* __restrict__ acc2, const float* __restrict__ h1,
    const float* __restrict__ Wout, const float* __restrict__ bias,
    float* __restrict__ out)
{
    const int b = blockIdx.x, tid = threadIdx.x;
    const int w = tid >> 6, lane = tid & 63;
    __shared__ float hh[2 * E_];
    const float linv = 1.f / acc2[B_ * E_ + b];
    if (tid < E_) {
        hh[tid]      = h1[b * E_ + tid];
        hh[E_ + tid] = acc2[b * E_ + tid] * linv;
    }
    __syncthreads();
    for (int c = w; c < C_; c += 5) {
        float p = 0.f;
        for (int e = lane; e < 2 * E_; e += 64)
            p += hh[e] * Wout[(size_t)e * C_ + c];
        #pragma unroll
        for (int off = 32; off > 0; off >>= 1) p += __shfl_xor(p, off);
        if (lane == 0) out[b * C_ + c] = p + bias[c];
    }
}

extern "C" void kernel_launch(void* const* d_in, const int* in_sizes, int n_in,
                              void* d_out, int out_size, void* d_ws, size_t ws_size,
                              hipStream_t stream) {
    const int*   x     = (const int*)  d_in[0];   // [64,2048]
    const float* emb   = (const float*)d_in[1];   // [50000,300]
    const float* query = (const float*)d_in[2];   // [1,300]
    const float* Watt  = (const float*)d_in[3];   // [300,150]
    const float* Wout  = (const float*)d_in[4];   // [600,34]
    const float* bias  = (const float*)d_in[5];   // [34]
    float* out = (float*)d_out;                   // [64,34]

    // ws: cnt 3.2MB ++ p_h 512*19264 fp32 (39.5MB) ++ acc1/acc2/h1/v2
    unsigned int*  cnt32 = (unsigned int*)d_ws;
    unsigned char* cntb  = (unsigned char*)d_ws;
    float* p_h  = (float*)((char*)d_ws + (size_t)NROWS * 64);
    float* acc1 = p_h + (size_t)PBLK * PJ;   // 19264
    float* acc2 = acc1 + PJ;                 // 19264
    float* h1   = acc2 + PJ;                 // 19200
    float* v2   = h1 + B_ * E_;              // 19200

    zero_cnt   <<<3125, 256, 0, stream>>>(cnt32);          // 800000 words
    scatter_cnt<<<512, 256, 0, stream>>>(x, cnt32);        // 131072 tokens
    stage1_pass<<<PBLK, 256, 0, stream>>>(emb, query, cntb, p_h);
    reduce_parts<<<PJ / 64, 256, 0, stream>>>(p_h, acc1);  // 301 blocks
    qv_kernel  <<<B_, 320, 0, stream>>>(acc1, Watt, h1, v2);
    stage2_pass<<<PBLK, 256, 0, stream>>>(emb, v2, cntb, p_h);
    reduce_parts<<<PJ / 64, 256, 0, stream>>>(p_h, acc2);
    scores_kernel<<<B_, 320, 0, stream>>>(acc2, h1, Wout, bias, out);
}